// Round 13
// baseline (301.838 us; speedup 1.0000x reference)
//
#include <hip/hip_runtime.h>

#define N_NODES 100000
#define E_EDGES 3200000

// ---- bucket geometry ----
#define BSHIFT 7
#define BWIDTH 128                       // src values per bucket
#define NBUCKETS 782                     // ceil(100000/128)
#define BCAP 5120                        // fixed slots/bucket (mean 4096 +16s)
#define NB1 400                          // partition blocks
#define CHUNK1 8000                      // NB1*CHUNK1 == E_EDGES exactly

// Wct: transposed fused weight matrix, bf16, [80 cols][264 k-stride]
#define WCT_STRIDE 264
#define WCT_ELEMS (80 * WCT_STRIDE)      // 21120 ushorts

#define N_TILES (N_NODES / 16)           // 6250
#define NSLOTS (NBUCKETS * BCAP)         // 4,003,840

// ---------------------------------------------------------------------------
// ws layout (float slots):
//   hem    [0,        3200000)   N*64 ushort bf16, PERMUTED: hem[d][r*4+n]
//   s8     [3200000,  4000000)   N*8 f32  [s_src+att_b (4) | s_dst (4)]
//   Wct    [4000000,  4010560)   21120 ushort
//   off8   [4010560,  4010568)   8 f32
//   rowptr [4010568,  4110568)   N ints (segment beg; end = beg + rowcnt)
//   rowcnt [4110568,  4210568)   N ints
//   gcur   [4210568,  4211368)   800 ints (per-bucket fill, memset 0)
//   sp     [4211368,  8215208)   NSLOTS ints (lsrc<<20|dst, sorted by src)
//   region [8215208, 16222888)   2*NSLOTS ints, time-shared:
//     pairs = region[0 : NSLOTS)        (bpart out, bsort in; then dead)
//     aw    = region[0 : 2*NSLOTS)      (wcalc out: 4x bf16 per slot)
// total 64.9 MB  (< 69.9 MB proven in R9)
// ---------------------------------------------------------------------------

typedef __attribute__((ext_vector_type(8))) short short8;
typedef __attribute__((ext_vector_type(4))) float f32x4;

__device__ __forceinline__ unsigned short f2bf(float f) {
    unsigned u = __float_as_uint(f);
    return (unsigned short)((u + 0x7FFFu + ((u >> 16) & 1u)) >> 16);  // RNE
}

// One wave per k (64 blocks x 4 waves): coalesced loads + shuffle reduce.
__global__ __launch_bounds__(256) void fuse_weights_kernel(
    const float* __restrict__ W_lin, const float* __restrict__ b_lin,
    const float* __restrict__ att_w, const float* __restrict__ emb_w,
    unsigned short* __restrict__ Wct, float* __restrict__ off8) {
    const int wave = threadIdx.x >> 6, lane = threadIdx.x & 63;
    const int k = blockIdx.x * 4 + wave;  // 0..255
    float4 wv = *(const float4*)(W_lin + k * 256 + lane * 4);
    float acc[8];
#pragma unroll
    for (int j = 0; j < 8; ++j) {
        int l = j & 3, part = j >> 2;
        float4 av = *(const float4*)(att_w + l * 512 + part * 256 + lane * 4);
        acc[j] = wv.x * av.x + wv.y * av.y + wv.z * av.z + wv.w * av.w;
    }
#pragma unroll
    for (int j = 0; j < 8; ++j) {
        float v = acc[j];
#pragma unroll
        for (int off = 32; off >= 1; off >>= 1) v += __shfl_xor(v, off);
        acc[j] = v;
    }
    if (lane < 8) {  // static-index select
        float v = acc[0];
#pragma unroll
        for (int j = 1; j < 8; ++j) if (lane == j) v = acc[j];
        Wct[(64 + lane) * WCT_STRIDE + k] = f2bf(v);
    }
    Wct[lane * WCT_STRIDE + k] = f2bf(emb_w[k * 64 + lane]);  // emb transpose
    if (lane < 8) Wct[(72 + lane) * WCT_STRIDE + k] = 0;
    if (k < 8) {  // off8[k] = b_lin . a_row(k)
        int l = k & 3, part = k >> 2;
        float4 av = *(const float4*)(att_w + l * 512 + part * 256 + lane * 4);
        float4 bv = *(const float4*)(b_lin + lane * 4);
        float p = bv.x * av.x + bv.y * av.y + bv.z * av.z + bv.w * av.w;
#pragma unroll
        for (int off = 32; off >= 1; off >>= 1) p += __shfl_xor(p, off);
        if (lane == 0) off8[k] = p;
    }
}

// MFMA row kernel: persistent-ish blocks (768 = 3/CU), wave-strided tiles.
// hem stored PERMUTED: hem[row][r*4+n] = value for original col 16n+r.
__global__ __launch_bounds__(256) void row_mfma_kernel(
    const float* __restrict__ x, const unsigned short* __restrict__ Wct,
    const float* __restrict__ off8, const float* __restrict__ att_b,
    const float* __restrict__ emb_b,
    unsigned short* __restrict__ hem, float* __restrict__ s8) {
    __shared__ unsigned short Wl[WCT_ELEMS];  // stride-264 (2-way, free)
    const int tid = threadIdx.x;
    for (int i = tid; i < WCT_ELEMS / 8; i += 256)
        ((uint4*)Wl)[i] = ((const uint4*)Wct)[i];
    __syncthreads();
    const int wave = tid >> 6, lane = tid & 63;
    const int r = lane & 15, g = lane >> 4;
    const int gw = blockIdx.x * 4 + wave, nw = gridDim.x * 4;
    for (int tile = gw; tile < N_TILES; tile += nw) {
        const int row0 = tile * 16;
        const float* xr = x + (size_t)(row0 + r) * 256 + g * 8;

        f32x4 acc[5];
#pragma unroll
        for (int n = 0; n < 5; ++n) acc[n] = (f32x4){0.f, 0.f, 0.f, 0.f};

        for (int kk = 0; kk < 8; ++kk) {
            float4 xa = *(const float4*)(xr + kk * 32);
            float4 xb = *(const float4*)(xr + kk * 32 + 4);
            short8 a;
            a[0] = (short)f2bf(xa.x); a[1] = (short)f2bf(xa.y);
            a[2] = (short)f2bf(xa.z); a[3] = (short)f2bf(xa.w);
            a[4] = (short)f2bf(xb.x); a[5] = (short)f2bf(xb.y);
            a[6] = (short)f2bf(xb.z); a[7] = (short)f2bf(xb.w);
            const int bk = kk * 32 + g * 8;
#pragma unroll
            for (int n = 0; n < 5; ++n) {
                short8 b = *(const short8*)(&Wl[(16 * n + r) * WCT_STRIDE + bk]);
                acc[n] = __builtin_amdgcn_mfma_f32_16x16x32_bf16(a, b, acc[n],
                                                                 0, 0, 0);
            }
        }
#pragma unroll
        for (int q = 0; q < 4; ++q) {
            const int orow = row0 + g * 4 + q;
            unsigned e0 = f2bf(acc[0][q] + emb_b[r]);
            unsigned e1 = f2bf(acc[1][q] + emb_b[16 + r]);
            unsigned e2 = f2bf(acc[2][q] + emb_b[32 + r]);
            unsigned e3 = f2bf(acc[3][q] + emb_b[48 + r]);
            uint2 hv;
            hv.x = e0 | (e1 << 16);
            hv.y = e2 | (e3 << 16);
            *(uint2*)(hem + (size_t)orow * 64 + r * 4) = hv;  // permuted row
            if (r < 8)
                s8[(size_t)orow * 8 + r] =
                    acc[4][q] + off8[r] + (r < 4 ? att_b[r] : 0.f);
        }
    }
}

// ---- partition: LDS hist -> global reservation -> scatter, ONE kernel ----
__global__ __launch_bounds__(256) void bpart_kernel(const int* __restrict__ src,
                                                    const int* __restrict__ dst,
                                                    int* __restrict__ gcur,
                                                    int* __restrict__ pairs) {
    __shared__ int h[NBUCKETS];
    for (int i = threadIdx.x; i < NBUCKETS; i += 256) h[i] = 0;
    __syncthreads();
    const int base = blockIdx.x * CHUNK1;
    for (int i = threadIdx.x; i < CHUNK1; i += 256)
        atomicAdd(&h[src[base + i] >> BSHIFT], 1);
    __syncthreads();
    for (int b = threadIdx.x; b < NBUCKETS; b += 256) {
        int c = h[b];
        h[b] = c ? atomicAdd(&gcur[b], c) : 0;  // reserve [h[b], h[b]+c)
    }
    __syncthreads();
    for (int i = threadIdx.x; i < CHUNK1; i += 256) {
        int s = src[base + i];
        int b = s >> BSHIFT;
        int pos = atomicAdd(&h[b], 1);  // walks reserved range
        pairs[b * BCAP + pos] = ((s & (BWIDTH - 1)) << 20) | dst[base + i];
    }
}

// ---- per-bucket counting sort; emits rowptr/rowcnt + sorted full pairs ----
__global__ __launch_bounds__(256) void bsort_kernel(const int* __restrict__ gcur,
                                                    const int* __restrict__ pairs,
                                                    int* __restrict__ sp,
                                                    int* __restrict__ rowptr,
                                                    int* __restrict__ rowcnt) {
    __shared__ int h[BWIDTH];
    const int b = blockIdx.x, t = threadIdx.x;
    const int beg = b * BCAP;
    const int end = beg + gcur[b];
    if (t < BWIDTH) h[t] = 0;
    __syncthreads();
    for (int i = beg + t; i < end; i += 256)
        atomicAdd(&h[pairs[i] >> 20], 1);
    __syncthreads();
    const int s0 = b << BSHIFT;
    if (t < BWIDTH && s0 + t < N_NODES) rowcnt[s0 + t] = h[t];
    __syncthreads();  // rowcnt reads h before the scan mutates it
    if (t == 0) {     // serial exclusive scan of 128 (cheap)
        int run = 0;
        for (int i = 0; i < BWIDTH; ++i) { int c = h[i]; h[i] = run; run += c; }
    }
    __syncthreads();
    if (t < BWIDTH && s0 + t < N_NODES) rowptr[s0 + t] = beg + h[t];
    __syncthreads();  // rowptr reads h before placement mutates it
    for (int i = beg + t; i < end; i += 256) {
        int p = pairs[i];
        int pos = beg + atomicAdd(&h[p >> 20], 1);
        sp[pos] = p;  // keep full (lsrc<<20|dst) for wcalc
    }
}

// ---- edge-parallel weight kernel: one thread per slot. Lanes map to EDGES,
// so trans cost is 12 per 64 edges (4x fewer wave trans-ops than computing
// in node's edge x head x replica layout). grid = (BCAP/256, NBUCKETS).
__global__ __launch_bounds__(256) void wcalc_kernel(
    const int* __restrict__ gcur, const int* __restrict__ sp,
    const float* __restrict__ s8, uint2* __restrict__ aw) {
    const int b = blockIdx.y;
    const int i = blockIdx.x * 256 + threadIdx.x;
    if (i >= gcur[b]) return;
    const unsigned pos = (unsigned)b * BCAP + i;
    const int p = sp[pos];
    const unsigned dst = (unsigned)(p & 0xFFFFF);
    const unsigned src = ((unsigned)b << BSHIFT) + (unsigned)(p >> 20);
    const float4 ss = *(const float4*)(s8 + src * 8u);       // +att_b folded
    const float4 sd = *(const float4*)(s8 + dst * 8u + 4u);
    const float w0 = __expf(1.f / (1.f + __expf(-(ss.x + sd.x))));
    const float w1 = __expf(1.f / (1.f + __expf(-(ss.y + sd.y))));
    const float w2 = __expf(1.f / (1.f + __expf(-(ss.z + sd.z))));
    const float w3 = __expf(1.f / (1.f + __expf(-(ss.w + sd.w))));
    uint2 v;  // truncated bf16 (numerator and ones-MFMA denominator share it)
    v.x = (__float_as_uint(w0) >> 16) | (__float_as_uint(w1) & 0xFFFF0000u);
    v.y = (__float_as_uint(w2) >> 16) | (__float_as_uint(w3) & 0xFFFF0000u);
    aw[pos] = v;
}

// ---- node kernel: no transcendentals, simple R11-style loop.
// Per j: sp load + 2B aw load + 8B permuted-hem load + packs. Denominator via
// 5th MFMA against constant-ones B (accd[q] = sum bf16(w[e,q]) on every lane).
// A rows replicated (head = r&3) -> all g-groups identical numerators;
// epilogue = 4 coalesced 256B stores.
__global__ __launch_bounds__(256) void node_kernel(
    const int* __restrict__ rowptr, const int* __restrict__ rowcnt,
    const int* __restrict__ sp, const unsigned short* __restrict__ aw,
    const unsigned short* __restrict__ hem, float* __restrict__ out) {
    const int lane = threadIdx.x & 63;
    const int r = lane & 15, g = lane >> 4, r3 = r & 3;
    const unsigned ru4 = (unsigned)(r * 4);
    const short8 bones = {16256, 16256, 16256, 16256,
                          16256, 16256, 16256, 16256};  // bf16 1.0 x8
    const int gw = (blockIdx.x * blockDim.x + threadIdx.x) >> 6;
    const int nw = (gridDim.x * blockDim.x) >> 6;
    for (int s = gw; s < N_NODES; s += nw) {
        const int beg = rowptr[s];
        const int deg = rowcnt[s];
        f32x4 a0 = {0.f, 0.f, 0.f, 0.f}, a1 = {0.f, 0.f, 0.f, 0.f};
        f32x4 a2 = {0.f, 0.f, 0.f, 0.f}, a3 = {0.f, 0.f, 0.f, 0.f};
        f32x4 ad = {0.f, 0.f, 0.f, 0.f};
        for (int off = 0; off < deg; off += 32) {
            const int m = deg - off;  // >=1
            short8 a, b0, b1, b2, b3;
#pragma unroll
            for (int j = 0; j < 8; ++j) {
                int e = 4 * j + g;
                const bool valid = (e < m);
                e = valid ? e : m - 1;                 // clamped, in-segment
                const unsigned pos = (unsigned)(beg + off + e);
                const unsigned dj = (unsigned)sp[pos] & 0xFFFFFu;
                const unsigned short wv = aw[pos * 4u + (unsigned)r3];
                a[j] = valid ? (short)wv : (short)0;
                const uint2 hv = *(const uint2*)(hem + dj * 64u + ru4);
                b0[j] = (short)(hv.x & 0xFFFFu);
                b1[j] = (short)(hv.x >> 16);
                b2[j] = (short)(hv.y & 0xFFFFu);
                b3[j] = (short)(hv.y >> 16);
            }
            a0 = __builtin_amdgcn_mfma_f32_16x16x32_bf16(a, b0, a0, 0, 0, 0);
            a1 = __builtin_amdgcn_mfma_f32_16x16x32_bf16(a, b1, a1, 0, 0, 0);
            a2 = __builtin_amdgcn_mfma_f32_16x16x32_bf16(a, b2, a2, 0, 0, 0);
            a3 = __builtin_amdgcn_mfma_f32_16x16x32_bf16(a, b3, a3, 0, 0, 0);
            ad = __builtin_amdgcn_mfma_f32_16x16x32_bf16(a, bones, ad, 0, 0, 0);
        }
        const float i0 = ad[0] > 0.f ? 1.f / ad[0] : 0.f;
        const float i1 = ad[1] > 0.f ? 1.f / ad[1] : 0.f;
        const float i2 = ad[2] > 0.f ? 1.f / ad[2] : 0.f;
        const float i3 = ad[3] > 0.f ? 1.f / ad[3] : 0.f;
        f32x4 av = a0;                   // g-group selects its column tile
        if (g == 1) av = a1;
        if (g == 2) av = a2;
        if (g == 3) av = a3;
        float* o = out + (size_t)s * 256 + g * 16 + r;
        o[0]   = av[0] * i0;
        o[64]  = av[1] * i1;
        o[128] = av[2] * i2;
        o[192] = av[3] * i3;
    }
}

extern "C" void kernel_launch(void* const* d_in, const int* in_sizes, int n_in,
                              void* d_out, int out_size, void* d_ws, size_t ws_size,
                              hipStream_t stream) {
    const float* x     = (const float*)d_in[0];
    const int*   src   = (const int*)d_in[1];
    const int*   dst   = (const int*)d_in[2];
    const float* W_lin = (const float*)d_in[3];
    const float* b_lin = (const float*)d_in[4];
    const float* att_w = (const float*)d_in[5];
    const float* att_b = (const float*)d_in[6];
    const float* emb_w = (const float*)d_in[7];
    const float* emb_b = (const float*)d_in[8];
    float* out = (float*)d_out;
    float* ws  = (float*)d_ws;

    unsigned short* hem = (unsigned short*)ws;
    float* s8     = ws + 3200000;
    unsigned short* Wct = (unsigned short*)(ws + 4000000);
    float* off8   = ws + 4010560;
    int*   rowptr = (int*)(ws + 4010568);
    int*   rowcnt = (int*)(ws + 4110568);
    int*   gcur   = (int*)(ws + 4210568);
    int*   sp     = (int*)(ws + 4211368);
    int*   pairs  = (int*)(ws + 8215208);   // dead after bsort
    uint2* aw     = (uint2*)(ws + 8215208); // overlays pairs (wcalc onward)

    hipMemsetAsync(gcur, 0, 800 * sizeof(int), stream);

    fuse_weights_kernel<<<64, 256, 0, stream>>>(W_lin, b_lin, att_w, emb_w,
                                                Wct, off8);
    row_mfma_kernel<<<768, 256, 0, stream>>>(x, Wct, off8, att_b, emb_b,
                                             hem, s8);
    bpart_kernel<<<NB1, 256, 0, stream>>>(src, dst, gcur, pairs);
    bsort_kernel<<<NBUCKETS, 256, 0, stream>>>(gcur, pairs, sp, rowptr,
                                               rowcnt);
    dim3 wgrid(BCAP / 256, NBUCKETS);
    wcalc_kernel<<<wgrid, 256, 0, stream>>>(gcur, sp, s8, aw);
    node_kernel<<<4096, 256, 0, stream>>>(rowptr, rowcnt, sp,
                                          (const unsigned short*)aw, hem, out);
}

// Round 14
// 292.942 us; speedup vs baseline: 1.0304x; 1.0304x over previous
//
#include <hip/hip_runtime.h>

#define N_NODES 100000
#define E_EDGES 3200000

// ---- bucket geometry ----
#define BSHIFT 7
#define BWIDTH 128                       // src values per bucket
#define NBUCKETS 782                     // ceil(100000/128)
#define BCAP 5120                        // fixed slots/bucket (mean 4096 +16s)
#define NB1 400                          // partition blocks
#define CHUNK1 8000                      // NB1*CHUNK1 == E_EDGES exactly

// Wct: transposed fused weight matrix, bf16, [80 cols][264 k-stride]
#define WCT_STRIDE 264
#define WCT_ELEMS (80 * WCT_STRIDE)      // 21120 ushorts

#define N_TILES (N_NODES / 16)           // 6250
#define N_GROUPS (N_NODES / 4)           // 25000 (4-node groups, bucket-aligned)

// ---------------------------------------------------------------------------
// ws layout (float slots):
//   hem    [0,        3200000)   N*64 ushort bf16, PERMUTED: hem[d][r*4+n]
//   s8     [3200000,  4000000)   N*8 f32  [s_src+att_b (4) | s_dst (4)]
//   Wct    [4000000,  4010560)   21120 ushort
//   off8   [4010560,  4010568)   8 f32
//   rowptr [4010568,  4110568)   N ints (segment beg; end = beg + rowcnt)
//   rowcnt [4110568,  4210568)   N ints
//   gcur   [4210568,  4211368)   800 ints (per-bucket fill, memset 0)
//   pairs  [4211368,  8215208)   NBUCKETS*BCAP ints (lsrc<<20 | dst)
//   sdst   [8215208, 12219048)   NBUCKETS*BCAP ints (dst sorted by src)
// total 48.9 MB
// ---------------------------------------------------------------------------

typedef __attribute__((ext_vector_type(8))) short short8;
typedef __attribute__((ext_vector_type(4))) float f32x4;

__device__ __forceinline__ unsigned short f2bf(float f) {
    unsigned u = __float_as_uint(f);
    return (unsigned short)((u + 0x7FFFu + ((u >> 16) & 1u)) >> 16);  // RNE
}

// One wave per k (64 blocks x 4 waves): coalesced loads + shuffle reduce.
__global__ __launch_bounds__(256) void fuse_weights_kernel(
    const float* __restrict__ W_lin, const float* __restrict__ b_lin,
    const float* __restrict__ att_w, const float* __restrict__ emb_w,
    unsigned short* __restrict__ Wct, float* __restrict__ off8) {
    const int wave = threadIdx.x >> 6, lane = threadIdx.x & 63;
    const int k = blockIdx.x * 4 + wave;  // 0..255
    float4 wv = *(const float4*)(W_lin + k * 256 + lane * 4);
    float acc[8];
#pragma unroll
    for (int j = 0; j < 8; ++j) {
        int l = j & 3, part = j >> 2;
        float4 av = *(const float4*)(att_w + l * 512 + part * 256 + lane * 4);
        acc[j] = wv.x * av.x + wv.y * av.y + wv.z * av.z + wv.w * av.w;
    }
#pragma unroll
    for (int j = 0; j < 8; ++j) {
        float v = acc[j];
#pragma unroll
        for (int off = 32; off >= 1; off >>= 1) v += __shfl_xor(v, off);
        acc[j] = v;
    }
    if (lane < 8) {  // static-index select
        float v = acc[0];
#pragma unroll
        for (int j = 1; j < 8; ++j) if (lane == j) v = acc[j];
        Wct[(64 + lane) * WCT_STRIDE + k] = f2bf(v);
    }
    Wct[lane * WCT_STRIDE + k] = f2bf(emb_w[k * 64 + lane]);  // emb transpose
    if (lane < 8) Wct[(72 + lane) * WCT_STRIDE + k] = 0;
    if (k < 8) {  // off8[k] = b_lin . a_row(k)
        int l = k & 3, part = k >> 2;
        float4 av = *(const float4*)(att_w + l * 512 + part * 256 + lane * 4);
        float4 bv = *(const float4*)(b_lin + lane * 4);
        float p = bv.x * av.x + bv.y * av.y + bv.z * av.z + bv.w * av.w;
#pragma unroll
        for (int off = 32; off >= 1; off >>= 1) p += __shfl_xor(p, off);
        if (lane == 0) off8[k] = p;
    }
}

// MFMA row kernel: persistent-ish blocks (768 = 3/CU), wave-strided tiles.
// hem stored PERMUTED: hem[row][r*4+n] = value for original col 16n+r.
__global__ __launch_bounds__(256) void row_mfma_kernel(
    const float* __restrict__ x, const unsigned short* __restrict__ Wct,
    const float* __restrict__ off8, const float* __restrict__ att_b,
    const float* __restrict__ emb_b,
    unsigned short* __restrict__ hem, float* __restrict__ s8) {
    __shared__ unsigned short Wl[WCT_ELEMS];  // stride-264 (2-way, free)
    const int tid = threadIdx.x;
    for (int i = tid; i < WCT_ELEMS / 8; i += 256)
        ((uint4*)Wl)[i] = ((const uint4*)Wct)[i];
    __syncthreads();
    const int wave = tid >> 6, lane = tid & 63;
    const int r = lane & 15, g = lane >> 4;
    const int gw = blockIdx.x * 4 + wave, nw = gridDim.x * 4;
    for (int tile = gw; tile < N_TILES; tile += nw) {
        const int row0 = tile * 16;
        const float* xr = x + (size_t)(row0 + r) * 256 + g * 8;

        f32x4 acc[5];
#pragma unroll
        for (int n = 0; n < 5; ++n) acc[n] = (f32x4){0.f, 0.f, 0.f, 0.f};

        for (int kk = 0; kk < 8; ++kk) {
            float4 xa = *(const float4*)(xr + kk * 32);
            float4 xb = *(const float4*)(xr + kk * 32 + 4);
            short8 a;
            a[0] = (short)f2bf(xa.x); a[1] = (short)f2bf(xa.y);
            a[2] = (short)f2bf(xa.z); a[3] = (short)f2bf(xa.w);
            a[4] = (short)f2bf(xb.x); a[5] = (short)f2bf(xb.y);
            a[6] = (short)f2bf(xb.z); a[7] = (short)f2bf(xb.w);
            const int bk = kk * 32 + g * 8;
#pragma unroll
            for (int n = 0; n < 5; ++n) {
                short8 b = *(const short8*)(&Wl[(16 * n + r) * WCT_STRIDE + bk]);
                acc[n] = __builtin_amdgcn_mfma_f32_16x16x32_bf16(a, b, acc[n],
                                                                 0, 0, 0);
            }
        }
#pragma unroll
        for (int q = 0; q < 4; ++q) {
            const int orow = row0 + g * 4 + q;
            unsigned e0 = f2bf(acc[0][q] + emb_b[r]);
            unsigned e1 = f2bf(acc[1][q] + emb_b[16 + r]);
            unsigned e2 = f2bf(acc[2][q] + emb_b[32 + r]);
            unsigned e3 = f2bf(acc[3][q] + emb_b[48 + r]);
            uint2 hv;
            hv.x = e0 | (e1 << 16);
            hv.y = e2 | (e3 << 16);
            *(uint2*)(hem + (size_t)orow * 64 + r * 4) = hv;  // permuted row
            if (r < 8)
                s8[(size_t)orow * 8 + r] =
                    acc[4][q] + off8[r] + (r < 4 ? att_b[r] : 0.f);
        }
    }
}

// ---- partition: LDS hist -> global reservation -> scatter, ONE kernel ----
__global__ __launch_bounds__(256) void bpart_kernel(const int* __restrict__ src,
                                                    const int* __restrict__ dst,
                                                    int* __restrict__ gcur,
                                                    int* __restrict__ pairs) {
    __shared__ int h[NBUCKETS];
    for (int i = threadIdx.x; i < NBUCKETS; i += 256) h[i] = 0;
    __syncthreads();
    const int base = blockIdx.x * CHUNK1;
    for (int i = threadIdx.x; i < CHUNK1; i += 256)
        atomicAdd(&h[src[base + i] >> BSHIFT], 1);
    __syncthreads();
    for (int b = threadIdx.x; b < NBUCKETS; b += 256) {
        int c = h[b];
        h[b] = c ? atomicAdd(&gcur[b], c) : 0;  // reserve [h[b], h[b]+c)
    }
    __syncthreads();
    for (int i = threadIdx.x; i < CHUNK1; i += 256) {
        int s = src[base + i];
        int b = s >> BSHIFT;
        int pos = atomicAdd(&h[b], 1);  // walks reserved range
        pairs[b * BCAP + pos] = ((s & (BWIDTH - 1)) << 20) | dst[base + i];
    }
}

// ---- per-bucket counting sort; emits rowptr (beg) + rowcnt + sorted dst ----
__global__ __launch_bounds__(256) void bsort_kernel(const int* __restrict__ gcur,
                                                    const int* __restrict__ pairs,
                                                    int* __restrict__ sdst,
                                                    int* __restrict__ rowptr,
                                                    int* __restrict__ rowcnt) {
    __shared__ int h[BWIDTH];
    const int b = blockIdx.x, t = threadIdx.x;
    const int beg = b * BCAP;
    const int end = beg + gcur[b];
    if (t < BWIDTH) h[t] = 0;
    __syncthreads();
    for (int i = beg + t; i < end; i += 256)
        atomicAdd(&h[pairs[i] >> 20], 1);
    __syncthreads();
    const int s0 = b << BSHIFT;
    if (t < BWIDTH && s0 + t < N_NODES) rowcnt[s0 + t] = h[t];
    __syncthreads();  // rowcnt reads h before the scan mutates it
    if (t == 0) {     // serial exclusive scan of 128 (cheap)
        int run = 0;
        for (int i = 0; i < BWIDTH; ++i) { int c = h[i]; h[i] = run; run += c; }
    }
    __syncthreads();
    if (t < BWIDTH && s0 + t < N_NODES) rowptr[s0 + t] = beg + h[t];
    __syncthreads();  // rowptr reads h before placement mutates it
    for (int i = beg + t; i < end; i += 256) {
        int p = pairs[i];
        int pos = beg + atomicAdd(&h[p >> 20], 1);
        sdst[pos] = p & 0xFFFFF;
    }
}

// ---- node kernel: 4 nodes per wave in the M dimension ----
// A-row = 4*node + head (16 distinct rows, no replication waste). A group of
// 4 consecutive nodes (aligned, so never straddling a bucket) has its edges
// CONTIGUOUS in sdst; we batch the union (T ~ Poisson(128)) in 32-edge MFMA
// steps: 24% fewer batches than per-node batching and 4x less tail waste.
// Lane (r,g): its A-rows' node is rn=r>>2, head r3=r&3; element j covers
// edge el = off+4j+g. a[j] = (edge's node == rn && valid) ? bf16(w) : 0,
// with w = exp(sigmoid(ssr(rn,r3) + sd(dj,r3))). B (hem) and C/D exactly as
// before. Ones-column MFMA gives node (s0+g)'s denominators in ad[q] on
// g-group lanes. Epilogue: lane (r,g) writes node s0+g, head q, cols 16n+r.
__global__ __launch_bounds__(256) void node_kernel(
    const int* __restrict__ rowptr, const int* __restrict__ rowcnt,
    const int* __restrict__ sdst, const float* __restrict__ s8,
    const unsigned short* __restrict__ hem, float* __restrict__ out) {
    const int lane = threadIdx.x & 63;
    const int r = lane & 15, g = lane >> 4, r3 = r & 3, rn = r >> 2;
    const unsigned ru4 = (unsigned)(r * 4);
    const short8 bones = {16256, 16256, 16256, 16256,
                          16256, 16256, 16256, 16256};  // bf16 1.0 x8
    const int gi = (blockIdx.x * blockDim.x + threadIdx.x) >> 6;  // 1 group/wave
    const int s0 = gi * 4;
    const int4 rp = *(const int4*)(rowptr + s0);
    const int ebeg = rp.x;
    const int o1 = rp.y - ebeg, o2 = rp.z - ebeg, o3 = rp.w - ebeg;
    const int T = o3 + rowcnt[s0 + 3];
    // this lane's src-score: node s0+rn, head r3 (+att_b folded)
    const float ssr = s8[(unsigned)(s0 + rn) * 8u + (unsigned)r3];
    f32x4 a0 = {0.f, 0.f, 0.f, 0.f}, a1 = {0.f, 0.f, 0.f, 0.f};
    f32x4 a2 = {0.f, 0.f, 0.f, 0.f}, a3 = {0.f, 0.f, 0.f, 0.f};
    f32x4 ad = {0.f, 0.f, 0.f, 0.f};
    for (int off = 0; off < T; off += 32) {
        const int m = T - off;  // >=1
        short8 a, b0, b1, b2, b3;
#pragma unroll
        for (int j = 0; j < 8; ++j) {
            const int e = 4 * j + g;
            const bool valid = (e < m);
            const int el = off + (valid ? e : m - 1);  // clamped local index
            const unsigned pos = (unsigned)(ebeg + el);
            const unsigned dj = (unsigned)sdst[pos];
            const float sd = s8[dj * 8u + 4u + (unsigned)r3];
            const float t = ssr + sd;
            const float sg = 1.f / (1.f + __expf(-t));
            float w = __expf(sg);
            const int ni = (el >= o1) + (el >= o2) + (el >= o3);
            w = (valid && ni == rn) ? w : 0.f;
            a[j] = (short)(__float_as_uint(w) >> 16);  // truncated bf16
            const uint2 hv = *(const uint2*)(hem + dj * 64u + ru4);
            b0[j] = (short)(hv.x & 0xFFFFu);
            b1[j] = (short)(hv.x >> 16);
            b2[j] = (short)(hv.y & 0xFFFFu);
            b3[j] = (short)(hv.y >> 16);
        }
        a0 = __builtin_amdgcn_mfma_f32_16x16x32_bf16(a, b0, a0, 0, 0, 0);
        a1 = __builtin_amdgcn_mfma_f32_16x16x32_bf16(a, b1, a1, 0, 0, 0);
        a2 = __builtin_amdgcn_mfma_f32_16x16x32_bf16(a, b2, a2, 0, 0, 0);
        a3 = __builtin_amdgcn_mfma_f32_16x16x32_bf16(a, b3, a3, 0, 0, 0);
        ad = __builtin_amdgcn_mfma_f32_16x16x32_bf16(a, bones, ad, 0, 0, 0);
    }
    const float i0 = ad[0] > 0.f ? 1.f / ad[0] : 0.f;
    const float i1 = ad[1] > 0.f ? 1.f / ad[1] : 0.f;
    const float i2 = ad[2] > 0.f ? 1.f / ad[2] : 0.f;
    const float i3 = ad[3] > 0.f ? 1.f / ad[3] : 0.f;
    float* o = out + (size_t)(s0 + g) * 256 + r;  // node s0+g
    o[0 * 64 + 0]  = a0[0] * i0; o[1 * 64 + 0]  = a0[1] * i1;
    o[2 * 64 + 0]  = a0[2] * i2; o[3 * 64 + 0]  = a0[3] * i3;
    o[0 * 64 + 16] = a1[0] * i0; o[1 * 64 + 16] = a1[1] * i1;
    o[2 * 64 + 16] = a1[2] * i2; o[3 * 64 + 16] = a1[3] * i3;
    o[0 * 64 + 32] = a2[0] * i0; o[1 * 64 + 32] = a2[1] * i1;
    o[2 * 64 + 32] = a2[2] * i2; o[3 * 64 + 32] = a2[3] * i3;
    o[0 * 64 + 48] = a3[0] * i0; o[1 * 64 + 48] = a3[1] * i1;
    o[2 * 64 + 48] = a3[2] * i2; o[3 * 64 + 48] = a3[3] * i3;
}

extern "C" void kernel_launch(void* const* d_in, const int* in_sizes, int n_in,
                              void* d_out, int out_size, void* d_ws, size_t ws_size,
                              hipStream_t stream) {
    const float* x     = (const float*)d_in[0];
    const int*   src   = (const int*)d_in[1];
    const int*   dst   = (const int*)d_in[2];
    const float* W_lin = (const float*)d_in[3];
    const float* b_lin = (const float*)d_in[4];
    const float* att_w = (const float*)d_in[5];
    const float* att_b = (const float*)d_in[6];
    const float* emb_w = (const float*)d_in[7];
    const float* emb_b = (const float*)d_in[8];
    float* out = (float*)d_out;
    float* ws  = (float*)d_ws;

    unsigned short* hem = (unsigned short*)ws;
    float* s8     = ws + 3200000;
    unsigned short* Wct = (unsigned short*)(ws + 4000000);
    float* off8   = ws + 4010560;
    int*   rowptr = (int*)(ws + 4010568);
    int*   rowcnt = (int*)(ws + 4110568);
    int*   gcur   = (int*)(ws + 4210568);
    int*   pairs  = (int*)(ws + 4211368);
    int*   sdst   = (int*)(ws + 8215208);

    hipMemsetAsync(gcur, 0, 800 * sizeof(int), stream);

    fuse_weights_kernel<<<64, 256, 0, stream>>>(W_lin, b_lin, att_w, emb_w,
                                                Wct, off8);
    row_mfma_kernel<<<768, 256, 0, stream>>>(x, Wct, off8, att_b, emb_b,
                                             hem, s8);
    bpart_kernel<<<NB1, 256, 0, stream>>>(src, dst, gcur, pairs);
    bsort_kernel<<<NBUCKETS, 256, 0, stream>>>(gcur, pairs, sdst, rowptr,
                                               rowcnt);
    node_kernel<<<N_GROUPS / 4, 256, 0, stream>>>(rowptr, rowcnt, sdst, s8,
                                                  hem, out);
}

// Round 15
// 252.791 us; speedup vs baseline: 1.1940x; 1.1588x over previous
//
#include <hip/hip_runtime.h>

#define N_NODES 100000
#define E_EDGES 3200000

// ---- bucket geometry ----
#define BSHIFT 7
#define BWIDTH 128                       // src values per bucket
#define NBUCKETS 782                     // ceil(100000/128)
#define BCAP 5120                        // fixed slots/bucket (mean 4096 +16s)
#define NB1 400                          // partition blocks
#define CHUNK1 8000                      // NB1*CHUNK1 == E_EDGES exactly

// Wct: transposed fused weight matrix, bf16, [80 cols][264 k-stride]
#define WCT_STRIDE 264
#define WCT_ELEMS (80 * WCT_STRIDE)      // 21120 ushorts

#define N_TILES (N_NODES / 16)           // 6250
#define ROW_BLOCKS 768                   // 3 per CU (LDS-limited)

// ---------------------------------------------------------------------------
// ws layout (float slots):
//   hem    [0,        3200000)   N*64 ushort bf16, PERMUTED: hem[d][r*4+n]
//   s8     [3200000,  4000000)   N*8 f32  [s_src+att_b (4) | s_dst (4)]
//   Wct    [4000000,  4010560)   21120 ushort
//   off8   [4010560,  4010568)   8 f32
//   rowptr [4010568,  4110568)   N ints (segment beg; end = beg + rowcnt)
//   rowcnt [4110568,  4210568)   N ints
//   gcur   [4210568,  4211368)   800 ints (per-bucket fill, memset 0)
//   pairs  [4211368,  8215208)   NBUCKETS*BCAP ints (lsrc<<20 | dst)
//   sdst   [8215208, 12219048)   NBUCKETS*BCAP ints (dst sorted by src)
// total 48.9 MB
// ---------------------------------------------------------------------------

typedef __attribute__((ext_vector_type(8))) short short8;
typedef __attribute__((ext_vector_type(4))) float f32x4;

__device__ __forceinline__ unsigned short f2bf(float f) {
    unsigned u = __float_as_uint(f);
    return (unsigned short)((u + 0x7FFFu + ((u >> 16) & 1u)) >> 16);  // RNE
}

// ===========================================================================
// K1 "prep": fuse_weights (blocks 0..63)  ||  bpart (blocks 64..463)
// Independent stages share one dispatch for overlap.
// ===========================================================================
__global__ __launch_bounds__(256) void prep_kernel(
    const float* __restrict__ W_lin, const float* __restrict__ b_lin,
    const float* __restrict__ att_w, const float* __restrict__ emb_w,
    unsigned short* __restrict__ Wct, float* __restrict__ off8,
    const int* __restrict__ src, const int* __restrict__ dst,
    int* __restrict__ gcur, int* __restrict__ pairs) {
    __shared__ int h[NBUCKETS];
    if (blockIdx.x < 64) {
        // ---- fuse_weights: one wave per k (k = bid*4 + wave) ----
        const int wave = threadIdx.x >> 6, lane = threadIdx.x & 63;
        const int k = blockIdx.x * 4 + wave;  // 0..255
        float4 wv = *(const float4*)(W_lin + k * 256 + lane * 4);
        float acc[8];
#pragma unroll
        for (int j = 0; j < 8; ++j) {
            int l = j & 3, part = j >> 2;
            float4 av = *(const float4*)(att_w + l * 512 + part * 256 + lane * 4);
            acc[j] = wv.x * av.x + wv.y * av.y + wv.z * av.z + wv.w * av.w;
        }
#pragma unroll
        for (int j = 0; j < 8; ++j) {
            float v = acc[j];
#pragma unroll
            for (int off = 32; off >= 1; off >>= 1) v += __shfl_xor(v, off);
            acc[j] = v;
        }
        if (lane < 8) {  // static-index select
            float v = acc[0];
#pragma unroll
            for (int j = 1; j < 8; ++j) if (lane == j) v = acc[j];
            Wct[(64 + lane) * WCT_STRIDE + k] = f2bf(v);
        }
        Wct[lane * WCT_STRIDE + k] = f2bf(emb_w[k * 64 + lane]);  // transpose
        if (lane < 8) Wct[(72 + lane) * WCT_STRIDE + k] = 0;
        if (k < 8) {  // off8[k] = b_lin . a_row(k)
            int l = k & 3, part = k >> 2;
            float4 av = *(const float4*)(att_w + l * 512 + part * 256 + lane * 4);
            float4 bv = *(const float4*)(b_lin + lane * 4);
            float p = bv.x * av.x + bv.y * av.y + bv.z * av.z + bv.w * av.w;
#pragma unroll
            for (int off = 32; off >= 1; off >>= 1) p += __shfl_xor(p, off);
            if (lane == 0) off8[k] = p;
        }
    } else {
        // ---- bpart: LDS hist -> global reservation -> scatter ----
        const int pb = blockIdx.x - 64;  // 0..NB1-1
        for (int i = threadIdx.x; i < NBUCKETS; i += 256) h[i] = 0;
        __syncthreads();
        const int base = pb * CHUNK1;
        for (int i = threadIdx.x; i < CHUNK1; i += 256)
            atomicAdd(&h[src[base + i] >> BSHIFT], 1);
        __syncthreads();
        for (int b = threadIdx.x; b < NBUCKETS; b += 256) {
            int c = h[b];
            h[b] = c ? atomicAdd(&gcur[b], c) : 0;  // reserve [h[b], h[b]+c)
        }
        __syncthreads();
        for (int i = threadIdx.x; i < CHUNK1; i += 256) {
            int s = src[base + i];
            int b = s >> BSHIFT;
            int pos = atomicAdd(&h[b], 1);  // walks reserved range
            pairs[b * BCAP + pos] = ((s & (BWIDTH - 1)) << 20) | dst[base + i];
        }
    }
}

// ===========================================================================
// K2 "mid": row_mfma  ||  bsort, block-interleaved (even->row, odd->bsort)
// so both kinds are co-resident immediately. bsort's 512B hist aliases the
// head of row's 42KB Wl (different blocks -> safe).
// ===========================================================================
__global__ __launch_bounds__(256) void mid_kernel(
    const float* __restrict__ x, const unsigned short* __restrict__ Wct,
    const float* __restrict__ off8, const float* __restrict__ att_b,
    const float* __restrict__ emb_b,
    unsigned short* __restrict__ hem, float* __restrict__ s8,
    const int* __restrict__ gcur, const int* __restrict__ pairs,
    int* __restrict__ sdst, int* __restrict__ rowptr,
    int* __restrict__ rowcnt) {
    __shared__ unsigned short Wl[WCT_ELEMS];  // 42.2 KB (row branch)
    int* h = (int*)Wl;                        // bsort branch alias (512 B)
    const int bid = blockIdx.x;
    // interleave: bid<1536: even->row(bid>>1), odd->bsort(bid>>1);
    //             bid>=1536: bsort(768 + bid-1536)
    const bool is_row = (bid < 2 * ROW_BLOCKS) && ((bid & 1) == 0);
    if (is_row) {
        const int rid = bid >> 1;  // 0..767
        const int tid = threadIdx.x;
        for (int i = tid; i < WCT_ELEMS / 8; i += 256)
            ((uint4*)Wl)[i] = ((const uint4*)Wct)[i];
        __syncthreads();
        const int wave = tid >> 6, lane = tid & 63;
        const int r = lane & 15, g = lane >> 4;
        const int gw = rid * 4 + wave, nw = ROW_BLOCKS * 4;
        for (int tile = gw; tile < N_TILES; tile += nw) {
            const int row0 = tile * 16;
            const float* xr = x + (size_t)(row0 + r) * 256 + g * 8;
            f32x4 acc[5];
#pragma unroll
            for (int n = 0; n < 5; ++n) acc[n] = (f32x4){0.f, 0.f, 0.f, 0.f};
            for (int kk = 0; kk < 8; ++kk) {
                float4 xa = *(const float4*)(xr + kk * 32);
                float4 xb = *(const float4*)(xr + kk * 32 + 4);
                short8 a;
                a[0] = (short)f2bf(xa.x); a[1] = (short)f2bf(xa.y);
                a[2] = (short)f2bf(xa.z); a[3] = (short)f2bf(xa.w);
                a[4] = (short)f2bf(xb.x); a[5] = (short)f2bf(xb.y);
                a[6] = (short)f2bf(xb.z); a[7] = (short)f2bf(xb.w);
                const int bk = kk * 32 + g * 8;
#pragma unroll
                for (int n = 0; n < 5; ++n) {
                    short8 b = *(const short8*)(&Wl[(16 * n + r) * WCT_STRIDE + bk]);
                    acc[n] = __builtin_amdgcn_mfma_f32_16x16x32_bf16(a, b, acc[n],
                                                                     0, 0, 0);
                }
            }
#pragma unroll
            for (int q = 0; q < 4; ++q) {
                const int orow = row0 + g * 4 + q;
                unsigned e0 = f2bf(acc[0][q] + emb_b[r]);
                unsigned e1 = f2bf(acc[1][q] + emb_b[16 + r]);
                unsigned e2 = f2bf(acc[2][q] + emb_b[32 + r]);
                unsigned e3 = f2bf(acc[3][q] + emb_b[48 + r]);
                uint2 hv;
                hv.x = e0 | (e1 << 16);
                hv.y = e2 | (e3 << 16);
                *(uint2*)(hem + (size_t)orow * 64 + r * 4) = hv;  // permuted
                if (r < 8)
                    s8[(size_t)orow * 8 + r] =
                        acc[4][q] + off8[r] + (r < 4 ? att_b[r] : 0.f);
            }
        }
    } else {
        const int b = (bid < 2 * ROW_BLOCKS) ? (bid >> 1)
                                             : (ROW_BLOCKS + bid - 2 * ROW_BLOCKS);
        const int t = threadIdx.x;
        const int beg = b * BCAP;
        const int end = beg + gcur[b];
        if (t < BWIDTH) h[t] = 0;
        __syncthreads();
        for (int i = beg + t; i < end; i += 256)
            atomicAdd(&h[pairs[i] >> 20], 1);
        __syncthreads();
        const int s0 = b << BSHIFT;
        if (t < BWIDTH && s0 + t < N_NODES) rowcnt[s0 + t] = h[t];
        __syncthreads();  // rowcnt reads h before the scan mutates it
        if (t == 0) {     // serial exclusive scan of 128 (cheap)
            int run = 0;
            for (int i = 0; i < BWIDTH; ++i) { int c = h[i]; h[i] = run; run += c; }
        }
        __syncthreads();
        if (t < BWIDTH && s0 + t < N_NODES) rowptr[s0 + t] = beg + h[t];
        __syncthreads();  // rowptr reads h before placement mutates it
        for (int i = beg + t; i < end; i += 256) {
            int p = pairs[i];
            int pos = beg + atomicAdd(&h[p >> 20], 1);
            sdst[pos] = p & 0xFFFFF;
        }
    }
}

// ===========================================================================
// node kernel — R11 proven-best structure (3-pass batched loads, unsigned
// 32-bit addressing, nfull/tail split, grid-stride TLP).
// ===========================================================================
template <int MASKED>
__device__ __forceinline__ void node_batch(
    const int* __restrict__ sdst, const float* __restrict__ s8,
    const unsigned short* __restrict__ hem,
    int base, int m, int g, unsigned ru4, int r3, float ssr,
    const short8& bones,
    f32x4& acc0, f32x4& acc1, f32x4& acc2, f32x4& acc3, f32x4& accd) {
    unsigned dj[8];
#pragma unroll
    for (int j = 0; j < 8; ++j) {
        int e = 4 * j + g;
        if (MASKED) e = min(e, m - 1);
        dj[j] = (unsigned)sdst[(unsigned)(base + e)];
    }
    float sd[8];
    uint2 hv[8];
#pragma unroll
    for (int j = 0; j < 8; ++j) {
        sd[j] = s8[dj[j] * 8u + 4u + (unsigned)r3];
        hv[j] = *(const uint2*)(hem + dj[j] * 64u + ru4);
    }
    short8 a, b0, b1, b2, b3;
#pragma unroll
    for (int j = 0; j < 8; ++j) {
        const float t = ssr + sd[j];
        const float sg = 1.f / (1.f + __expf(-t));
        float w = __expf(sg);
        if (MASKED) w = (4 * j + g < m) ? w : 0.f;
        a[j] = (short)(__float_as_uint(w) >> 16);  // truncated bf16
        b0[j] = (short)(hv[j].x & 0xFFFFu);
        b1[j] = (short)(hv[j].x >> 16);
        b2[j] = (short)(hv[j].y & 0xFFFFu);
        b3[j] = (short)(hv[j].y >> 16);
    }
    acc0 = __builtin_amdgcn_mfma_f32_16x16x32_bf16(a, b0, acc0, 0, 0, 0);
    acc1 = __builtin_amdgcn_mfma_f32_16x16x32_bf16(a, b1, acc1, 0, 0, 0);
    acc2 = __builtin_amdgcn_mfma_f32_16x16x32_bf16(a, b2, acc2, 0, 0, 0);
    acc3 = __builtin_amdgcn_mfma_f32_16x16x32_bf16(a, b3, acc3, 0, 0, 0);
    accd = __builtin_amdgcn_mfma_f32_16x16x32_bf16(a, bones, accd, 0, 0, 0);
}

__global__ __launch_bounds__(256) void node_kernel(
    const int* __restrict__ rowptr, const int* __restrict__ rowcnt,
    const int* __restrict__ sdst, const float* __restrict__ s8,
    const unsigned short* __restrict__ hem, float* __restrict__ out) {
    const int lane = threadIdx.x & 63;
    const int r = lane & 15, g = lane >> 4, r3 = r & 3;
    const unsigned ru4 = (unsigned)(r * 4);
    const short8 bones = {16256, 16256, 16256, 16256,
                          16256, 16256, 16256, 16256};  // bf16 1.0 x8
    const int gw = (blockIdx.x * blockDim.x + threadIdx.x) >> 6;
    const int nw = (gridDim.x * blockDim.x) >> 6;
    for (int s = gw; s < N_NODES; s += nw) {
        const int beg = rowptr[s];
        const int deg = rowcnt[s];
        const float ssr = s8[(unsigned)s * 8u + (unsigned)r3];  // +att_b
        f32x4 a0 = {0.f, 0.f, 0.f, 0.f}, a1 = {0.f, 0.f, 0.f, 0.f};
        f32x4 a2 = {0.f, 0.f, 0.f, 0.f}, a3 = {0.f, 0.f, 0.f, 0.f};
        f32x4 ad = {0.f, 0.f, 0.f, 0.f};
        const int nfull = deg >> 5;
        int base = beg;
        for (int f = 0; f < nfull; ++f, base += 32)
            node_batch<0>(sdst, s8, hem, base, 32, g, ru4, r3, ssr, bones,
                          a0, a1, a2, a3, ad);
        const int m = deg - (base - beg);
        if (m > 0)
            node_batch<1>(sdst, s8, hem, base, m, g, ru4, r3, ssr, bones,
                          a0, a1, a2, a3, ad);
        const float i0 = ad[0] > 0.f ? 1.f / ad[0] : 0.f;
        const float i1 = ad[1] > 0.f ? 1.f / ad[1] : 0.f;
        const float i2 = ad[2] > 0.f ? 1.f / ad[2] : 0.f;
        const float i3 = ad[3] > 0.f ? 1.f / ad[3] : 0.f;
        f32x4 av = a0;                   // g-group selects its column tile
        if (g == 1) av = a1;
        if (g == 2) av = a2;
        if (g == 3) av = a3;
        float* o = out + (size_t)s * 256 + g * 16 + r;
        o[0]   = av[0] * i0;
        o[64]  = av[1] * i1;
        o[128] = av[2] * i2;
        o[192] = av[3] * i3;
    }
}

extern "C" void kernel_launch(void* const* d_in, const int* in_sizes, int n_in,
                              void* d_out, int out_size, void* d_ws, size_t ws_size,
                              hipStream_t stream) {
    const float* x     = (const float*)d_in[0];
    const int*   src   = (const int*)d_in[1];
    const int*   dst   = (const int*)d_in[2];
    const float* W_lin = (const float*)d_in[3];
    const float* b_lin = (const float*)d_in[4];
    const float* att_w = (const float*)d_in[5];
    const float* att_b = (const float*)d_in[6];
    const float* emb_w = (const float*)d_in[7];
    const float* emb_b = (const float*)d_in[8];
    float* out = (float*)d_out;
    float* ws  = (float*)d_ws;

    unsigned short* hem = (unsigned short*)ws;
    float* s8     = ws + 3200000;
    unsigned short* Wct = (unsigned short*)(ws + 4000000);
    float* off8   = ws + 4010560;
    int*   rowptr = (int*)(ws + 4010568);
    int*   rowcnt = (int*)(ws + 4110568);
    int*   gcur   = (int*)(ws + 4210568);
    int*   pairs  = (int*)(ws + 4211368);
    int*   sdst   = (int*)(ws + 8215208);

    hipMemsetAsync(gcur, 0, 800 * sizeof(int), stream);

    prep_kernel<<<64 + NB1, 256, 0, stream>>>(W_lin, b_lin, att_w, emb_w,
                                              Wct, off8, src, dst, gcur, pairs);
    mid_kernel<<<2 * ROW_BLOCKS + (NBUCKETS - ROW_BLOCKS), 256, 0, stream>>>(
        x, Wct, off8, att_b, emb_b, hem, s8, gcur, pairs, sdst, rowptr, rowcnt);
    node_kernel<<<4096, 256, 0, stream>>>(rowptr, rowcnt, sdst, s8, hem, out);
}